// Round 2
// baseline (129.280 us; speedup 1.0000x reference)
//
#include <hip/hip_runtime.h>
#include <hip/hip_bf16.h>

#define NEG 0.2f

typedef __attribute__((ext_vector_type(8))) short bf16x8;
typedef __attribute__((ext_vector_type(4))) float f32x4;
typedef __attribute__((ext_vector_type(4))) int int4v;

__device__ __forceinline__ float lrelu(float t){ return t > 0.f ? t : NEG * t; }

__device__ __forceinline__ unsigned short f2bf(float f){
  union { float f; unsigned int u; } v; v.f = f;
  unsigned int r = v.u + 0x7FFFu + ((v.u >> 16) & 1u);
  return (unsigned short)(r >> 16);
}

// ---------------- K1: fused h=x@W (regs only) + s_src/s_dst + bf16 transpose ht ----------------
// grid 512 (32 rows each), 256 thr. h is NEVER written to global (saves 24 MB traffic).
__global__ __launch_bounds__(256) void k1_fused(const float* __restrict__ x,
                                                const float* __restrict__ W,
                                                const float* __restrict__ a,
                                                unsigned short* __restrict__ ht,
                                                float* __restrict__ ssrc,
                                                float* __restrict__ sdst){
  __shared__ __align__(16) float Wl[128*128];          // 64 KB
  __shared__ __align__(16) float xl[32*136];           // 17 KB
  __shared__ __align__(16) unsigned short tl[128*34];  // 8.5 KB transpose tile (stride 34: bank-spread)
  const int t = threadIdx.x;
  const int bx = blockIdx.x;                 // b*64 + jt
  const int b  = bx >> 6;
  const int jt = bx & 63;
  const long rowbase = (long)bx * 32;
  {
    const f32x4* W4 = (const f32x4*)W;
    f32x4* Wl4 = (f32x4*)Wl;
#pragma unroll
    for (int i = 0; i < 16; ++i) Wl4[t + 256*i] = W4[t + 256*i];
    const int r = t >> 3, seg = t & 7;
    const f32x4* xs = (const f32x4*)(x + (rowbase + r)*128 + seg*16);
    f32x4* xd = (f32x4*)(xl + r*136 + seg*16);
#pragma unroll
    for (int i = 0; i < 4; ++i) xd[i] = xs[i];
  }
  __syncthreads();
  const int r = t >> 3, c = t & 7;
  f32x4 zro = {0.f, 0.f, 0.f, 0.f};
  f32x4 a0 = zro, a1 = zro, a2 = zro, a3 = zro;
  const float* xr = xl + r*136;
#pragma unroll 4
  for (int k = 0; k < 128; ++k){
    const float xv = xr[k];
    const f32x4* wk = (const f32x4*)(Wl + k*128 + c*16);
    a0 += xv * wk[0]; a1 += xv * wk[1]; a2 += xv * wk[2]; a3 += xv * wk[3];
  }
  // ---- s_src / s_dst: dot h-row with a vectors, reduce over the 8 col-threads ----
  {
    const f32x4* as4 = (const f32x4*)(a + c*16);
    const f32x4* ad4 = (const f32x4*)(a + 128 + c*16);
    f32x4 s0 = a0*as4[0] + a1*as4[1] + a2*as4[2] + a3*as4[3];
    f32x4 d0 = a0*ad4[0] + a1*ad4[1] + a2*ad4[2] + a3*ad4[3];
    float ps = s0[0]+s0[1]+s0[2]+s0[3];
    float pd = d0[0]+d0[1]+d0[2]+d0[3];
    ps += __shfl_down(ps, 4); pd += __shfl_down(pd, 4);
    ps += __shfl_down(ps, 2); pd += __shfl_down(pd, 2);
    ps += __shfl_down(ps, 1); pd += __shfl_down(pd, 1);
    if (c == 0){
      ssrc[rowbase + r] = ps;
      sdst[rowbase + r] = pd;
    }
  }
  // ---- transpose to bf16 ht[b][o][j] via LDS ----
  {
    float hv[16];
    *(f32x4*)&hv[0] = a0; *(f32x4*)&hv[4] = a1; *(f32x4*)&hv[8] = a2; *(f32x4*)&hv[12] = a3;
#pragma unroll
    for (int e = 0; e < 16; ++e) tl[(c*16 + e)*34 + r] = f2bf(hv[e]);
  }
  __syncthreads();
  {
    const int o = t >> 1, jseg = (t & 1) * 16;
    const unsigned int* src = (const unsigned int*)(tl + o*34 + jseg);
    unsigned int p[8];
#pragma unroll
    for (int i = 0; i < 8; ++i) p[i] = src[i];
    unsigned short* dst = ht + (long)b*262144 + (long)o*2048 + jt*32 + jseg;
    ((int4v*)dst)[0] = *(int4v*)&p[0];
    ((int4v*)dst)[1] = *(int4v*)&p[4];
  }
}

// ---------------- K2: per-row m_i and 1/l_i (in-wave batch max, two passes over L1-hot sdst) ----------------
__global__ __launch_bounds__(256) void k2_ml(const float* __restrict__ ssrc,
                                             const float* __restrict__ sdst,
                                             float* __restrict__ marr,
                                             float* __restrict__ rlarr){
  const int lane = threadIdx.x & 63;
  const long row = (long)blockIdx.x * 4 + (threadIdx.x >> 6);
  const int b = (int)(row >> 11);
  const float si = ssrc[row];
  const float* sd = sdst + (long)b*2048;
  float mx = -3.4e38f;
  for (int j = lane; j < 2048; j += 64) mx = fmaxf(mx, sd[j]);
#pragma unroll
  for (int off = 1; off <= 32; off <<= 1) mx = fmaxf(mx, __shfl_xor(mx, off));
  const float m = lrelu(si + mx);
  float sum = 0.f;
  for (int j = lane; j < 2048; j += 64)
    sum += __expf(lrelu(si + sd[j]) - m);
#pragma unroll
  for (int off = 1; off <= 32; off <<= 1) sum += __shfl_xor(sum, off);
  if (lane == 0){ marr[row] = m; rlarr[row] = 1.f / sum; }
}

// ---------------- K3: out = LR( (adj + alpha) @ h ), split-K x2, no in-loop barriers ----------------
// grid: 8 b * 32 tiles (BM=64); block 512 = 8 waves (2/SIMD). kh=wid>>2 takes K-half, wr=wid&3 takes 16 rows.
// ht read straight from global (L2-resident, 512 KB/batch) -> no LDS staging, no barriers in main loop.
__global__ __launch_bounds__(512, 2) void k3_main(const float* __restrict__ adj,
                                                  const unsigned short* __restrict__ ht,
                                                  const float* __restrict__ ssrc,
                                                  const float* __restrict__ sdst,
                                                  const float* __restrict__ marr,
                                                  const float* __restrict__ rlarr,
                                                  float* __restrict__ out){
  __shared__ __align__(16) float red[64*128];   // 32 KB, epilogue split-K reduction only
  const int t   = threadIdx.x;
  const int bx  = blockIdx.x;
  const int b   = bx >> 5;
  const int i0  = (bx & 31) * 64;
  const int wid = t >> 6, lane = t & 63;
  const int lr  = lane & 15, hi = lane >> 4;
  const int kh  = wid >> 2, wr = wid & 3;
  const int rowi = i0 + wr*16 + lr;
  const long rowg = (long)b*2048 + rowi;
  const float m_i  = marr[rowg];
  const float rl_i = rlarr[rowg];
  const float si   = ssrc[rowg];
  const float* adjrow = adj + rowg*2048 + kh*1024 + hi*8;
  const float* sdb    = sdst + (long)b*2048 + kh*1024 + hi*8;
  const unsigned short* htb = ht + (long)b*262144 + kh*1024 + hi*8;

  f32x4 zro = {0.f, 0.f, 0.f, 0.f};
  f32x4 acc[8];
#pragma unroll
  for (int i = 0; i < 8; ++i) acc[i] = zro;

  // prefetch step 0 (adj: HBM; sdst: L1)
  f32x4 av0 = *(const f32x4*)(adjrow);
  f32x4 av1 = *(const f32x4*)(adjrow + 4);
  f32x4 sd0 = *(const f32x4*)(sdb);
  f32x4 sd1 = *(const f32x4*)(sdb + 4);

  for (int kt = 0; kt < 32; ++kt){
    const int jo = kt * 32;
    const int jn = (kt < 31 ? kt + 1 : kt) * 32;
    f32x4 nav0 = *(const f32x4*)(adjrow + jn);
    f32x4 nav1 = *(const f32x4*)(adjrow + jn + 4);
    f32x4 nsd0 = *(const f32x4*)(sdb + jn);
    f32x4 nsd1 = *(const f32x4*)(sdb + jn + 4);

    // weights: w_ij = adj_ij + exp(LR(si+sj) - m_i) * rl_i, directly in A-fragment layout
    float wv[8];
    wv[0] = av0[0] + __expf(lrelu(si + sd0[0]) - m_i) * rl_i;
    wv[1] = av0[1] + __expf(lrelu(si + sd0[1]) - m_i) * rl_i;
    wv[2] = av0[2] + __expf(lrelu(si + sd0[2]) - m_i) * rl_i;
    wv[3] = av0[3] + __expf(lrelu(si + sd0[3]) - m_i) * rl_i;
    wv[4] = av1[0] + __expf(lrelu(si + sd1[0]) - m_i) * rl_i;
    wv[5] = av1[1] + __expf(lrelu(si + sd1[1]) - m_i) * rl_i;
    wv[6] = av1[2] + __expf(lrelu(si + sd1[2]) - m_i) * rl_i;
    wv[7] = av1[3] + __expf(lrelu(si + sd1[3]) - m_i) * rl_i;
    bf16x8 af;
#pragma unroll
    for (int e = 0; e < 8; ++e) af[e] = (short)f2bf(wv[e]);

#pragma unroll
    for (int cg = 0; cg < 8; ++cg){
      const bf16x8 bf = *(const bf16x8*)(htb + (long)(cg*16 + lr)*2048 + jo);
      acc[cg] = __builtin_amdgcn_mfma_f32_16x16x32_bf16(af, bf, acc[cg], 0, 0, 0);
    }

    av0 = nav0; av1 = nav1;
    sd0 = nsd0; sd1 = nsd1;
  }

  // epilogue: split-K reduce via LDS, then lrelu + store
  if (kh == 1){
#pragma unroll
    for (int cg = 0; cg < 8; ++cg)
#pragma unroll
      for (int q = 0; q < 4; ++q)
        red[(wr*16 + hi*4 + q)*128 + cg*16 + lr] = acc[cg][q];
  }
  __syncthreads();
  if (kh == 0){
#pragma unroll
    for (int cg = 0; cg < 8; ++cg){
#pragma unroll
      for (int q = 0; q < 4; ++q){
        const int rl2 = wr*16 + hi*4 + q;
        const float v = acc[cg][q] + red[rl2*128 + cg*16 + lr];
        out[((long)b*2048 + i0 + rl2)*128 + cg*16 + lr] = lrelu(v);
      }
    }
  }
}

extern "C" void kernel_launch(void* const* d_in, const int* in_sizes, int n_in,
                              void* d_out, int out_size, void* d_ws, size_t ws_size,
                              hipStream_t stream){
  const float* x   = (const float*)d_in[0];
  const float* adj = (const float*)d_in[1];
  const float* W   = (const float*)d_in[2];
  const float* a   = (const float*)d_in[3];
  float* out = (float*)d_out;
  char* ws = (char*)d_ws;

  unsigned short* ht   = (unsigned short*)(ws);               // 4 MB: [8][128][2048] bf16
  float*          ssrc = (float*)(ws + 4194304);              // 64 KB
  float*          sdst = (float*)(ws + 4259840);              // 64 KB
  float*          marr = (float*)(ws + 4325376);              // 64 KB
  float*          rlarr= (float*)(ws + 4390912);              // 64 KB

  k1_fused<<<512,  256, 0, stream>>>(x, W, a, ht, ssrc, sdst);
  k2_ml   <<<4096, 256, 0, stream>>>(ssrc, sdst, marr, rlarr);
  k3_main <<<256,  512, 0, stream>>>(adj, ht, ssrc, sdst, marr, rlarr, out);
}

// Round 3
// 64.613 us; speedup vs baseline: 2.0009x; 2.0009x over previous
//
#include <hip/hip_runtime.h>
#include <hip/hip_bf16.h>

#define NEG 0.2f
#define LOG2E 1.4426950408889634f

typedef __attribute__((ext_vector_type(8))) short bf16x8;
typedef __attribute__((ext_vector_type(4))) float f32x4;
typedef __attribute__((ext_vector_type(4))) int int4v;

__device__ __forceinline__ float lrelu(float t){ return fmaxf(t, NEG * t); }
__device__ __forceinline__ float fast_exp2(float x){
  float r; asm("v_exp_f32 %0, %1" : "=v"(r) : "v"(x)); return r;
}
__device__ __forceinline__ unsigned short f2bf(float f){   // RNE, used for ht only
  union { float f; unsigned int u; } v; v.f = f;
  unsigned int r = v.u + 0x7FFFu + ((v.u >> 16) & 1u);
  return (unsigned short)(r >> 16);
}

// ---------------- K1: fused h=x@W (regs) + scaled s_src/s_dst + bf16 transpose ht ----------------
__global__ __launch_bounds__(256) void k1_fused(const float* __restrict__ x,
                                                const float* __restrict__ W,
                                                const float* __restrict__ a,
                                                unsigned short* __restrict__ ht,
                                                float* __restrict__ ssrcL,
                                                float* __restrict__ sdstL){
  __shared__ __align__(16) float Wl[128*128];
  __shared__ __align__(16) float xl[32*136];
  __shared__ __align__(16) unsigned short tl[128*34];
  const int t = threadIdx.x;
  const int bx = blockIdx.x;                 // b*64 + jt
  const int b  = bx >> 6;
  const int jt = bx & 63;
  const long rowbase = (long)bx * 32;
  {
    const f32x4* W4 = (const f32x4*)W;
    f32x4* Wl4 = (f32x4*)Wl;
#pragma unroll
    for (int i = 0; i < 16; ++i) Wl4[t + 256*i] = W4[t + 256*i];
    const int r = t >> 3, seg = t & 7;
    const f32x4* xs = (const f32x4*)(x + (rowbase + r)*128 + seg*16);
    f32x4* xd = (f32x4*)(xl + r*136 + seg*16);
#pragma unroll
    for (int i = 0; i < 4; ++i) xd[i] = xs[i];
  }
  __syncthreads();
  const int r = t >> 3, c = t & 7;
  f32x4 zro = {0.f, 0.f, 0.f, 0.f};
  f32x4 a0 = zro, a1 = zro, a2 = zro, a3 = zro;
  const float* xr = xl + r*136;
#pragma unroll 4
  for (int k = 0; k < 128; ++k){
    const float xv = xr[k];
    const f32x4* wk = (const f32x4*)(Wl + k*128 + c*16);
    a0 += xv * wk[0]; a1 += xv * wk[1]; a2 += xv * wk[2]; a3 += xv * wk[3];
  }
  {
    const f32x4* as4 = (const f32x4*)(a + c*16);
    const f32x4* ad4 = (const f32x4*)(a + 128 + c*16);
    f32x4 s0 = a0*as4[0] + a1*as4[1] + a2*as4[2] + a3*as4[3];
    f32x4 d0 = a0*ad4[0] + a1*ad4[1] + a2*ad4[2] + a3*ad4[3];
    float ps = s0[0]+s0[1]+s0[2]+s0[3];
    float pd = d0[0]+d0[1]+d0[2]+d0[3];
    ps += __shfl_down(ps, 4); pd += __shfl_down(pd, 4);
    ps += __shfl_down(ps, 2); pd += __shfl_down(pd, 2);
    ps += __shfl_down(ps, 1); pd += __shfl_down(pd, 1);
    if (c == 0){
      ssrcL[rowbase + r] = ps * LOG2E;   // scaled domain: everything downstream is base-2
      sdstL[rowbase + r] = pd * LOG2E;
    }
  }
  {
    float hv[16];
    *(f32x4*)&hv[0] = a0; *(f32x4*)&hv[4] = a1; *(f32x4*)&hv[8] = a2; *(f32x4*)&hv[12] = a3;
#pragma unroll
    for (int e = 0; e < 16; ++e) tl[(c*16 + e)*34 + r] = f2bf(hv[e]);
  }
  __syncthreads();
  {
    const int o = t >> 1, jseg = (t & 1) * 16;
    const unsigned int* src = (const unsigned int*)(tl + o*34 + jseg);
    unsigned int p[8];
#pragma unroll
    for (int i = 0; i < 8; ++i) p[i] = src[i];
    unsigned short* dst = ht + (long)b*262144 + (long)o*2048 + jt*32 + jseg;
    ((int4v*)dst)[0] = *(int4v*)&p[0];
    ((int4v*)dst)[1] = *(int4v*)&p[4];
  }
}

// ---------------- K2: per-row C_i = m_L + log2(sum_j 2^(lrelu(siL+sjL)-m_L)) ----------------
__global__ __launch_bounds__(256) void k2_ml(const float* __restrict__ ssrcL,
                                             const float* __restrict__ sdstL,
                                             float* __restrict__ carr){
  const int lane = threadIdx.x & 63;
  const long row = (long)blockIdx.x * 4 + (threadIdx.x >> 6);
  const int b = (int)(row >> 11);
  const float siL = ssrcL[row];
  const float* sd = sdstL + (long)b*2048;
  float mx = -3.4e38f;
#pragma unroll
  for (int k = 0; k < 8; ++k){
    f32x4 v = *(const f32x4*)(sd + lane*4 + k*256);
    mx = fmaxf(mx, fmaxf(fmaxf(v[0], v[1]), fmaxf(v[2], v[3])));
  }
#pragma unroll
  for (int off = 1; off <= 32; off <<= 1) mx = fmaxf(mx, __shfl_xor(mx, off));
  const float mL = lrelu(siL + mx);
  float sum = 0.f;
#pragma unroll
  for (int k = 0; k < 8; ++k){
    f32x4 v = *(const f32x4*)(sd + lane*4 + k*256);
#pragma unroll
    for (int e = 0; e < 4; ++e) sum += fast_exp2(lrelu(siL + v[e]) - mL);
  }
#pragma unroll
  for (int off = 1; off <= 32; off <<= 1) sum += __shfl_xor(sum, off);
  if (lane == 0) carr[row] = mL + __log2f(sum);
}

// ---------------- K3: out = LR( (adj + alpha) @ h ) ----------------
// grid 256 = 8b*32 tiles (BM=64); block 512 = 8 waves; split-K x2 (kh), 4 row-waves (wr).
// ht double-buffered in LDS (one raw barrier per K-step, prefetches live across barriers).
__global__ __launch_bounds__(512) void k3_main(const float* __restrict__ adj,
                                               const unsigned short* __restrict__ ht,
                                               const float* __restrict__ ssrcL,
                                               const float* __restrict__ sdstL,
                                               const float* __restrict__ carr,
                                               float* __restrict__ out){
  __shared__ __align__(16) unsigned short tl[2][2][128*40];  // [buf][kh][o*40+j], 40 KB
  __shared__ __align__(16) float red[64*128];                // 32 KB epilogue
  const int t   = threadIdx.x;
  const int bx  = blockIdx.x;
  const int b   = bx >> 5;
  const int i0  = (bx & 31) * 64;
  const int lane = t & 63;
  const int lr  = lane & 15, hi = lane >> 4;
  const int kh  = t >> 8, wr = (t >> 6) & 3;
  const int rowi = i0 + wr*16 + lr;
  const long rowg = (long)b*2048 + rowi;
  const float siL = ssrcL[rowg];
  const float Ci  = carr[rowg];
  const float* adjrow = adj + rowg*2048 + kh*1024 + hi*8;
  const float* sdb    = sdstL + (long)b*2048 + kh*1024 + hi*8;
  const unsigned short* htg = ht + (long)b*262144;
  const int so = t >> 2, sseg = t & 3;                 // staging: row so, 16B seg
  const unsigned short* sgp = htg + (long)so*2048 + sseg*8;
  const int woff = so*40 + sseg*8;

  f32x4 zro = {0.f, 0.f, 0.f, 0.f};
  f32x4 acc[8];
#pragma unroll
  for (int i = 0; i < 8; ++i) acc[i] = zro;

  // ---- prologue: tile0 -> buf0; tiles 1,2 -> regs; adj/sd steps 0,1 -> regs ----
  int4v t0a = *(const int4v*)(sgp);
  int4v t0b = *(const int4v*)(sgp + 1024);
  *(int4v*)(&tl[0][0][woff]) = t0a;
  *(int4v*)(&tl[0][1][woff]) = t0b;
  int4v sA0 = *(const int4v*)(sgp + 32);
  int4v sA1 = *(const int4v*)(sgp + 1024 + 32);
  int4v sB0 = *(const int4v*)(sgp + 64);
  int4v sB1 = *(const int4v*)(sgp + 1024 + 64);
  f32x4 aA0 = *(const f32x4*)(adjrow);
  f32x4 aA1 = *(const f32x4*)(adjrow + 4);
  f32x4 dA0 = *(const f32x4*)(sdb);
  f32x4 dA1 = *(const f32x4*)(sdb + 4);
  f32x4 aB0 = *(const f32x4*)(adjrow + 32);
  f32x4 aB1 = *(const f32x4*)(adjrow + 36);
  f32x4 dB0 = *(const f32x4*)(sdb + 32);
  f32x4 dB1 = *(const f32x4*)(sdb + 36);
  asm volatile("s_waitcnt lgkmcnt(0)" ::: "memory");
  __builtin_amdgcn_s_barrier();
  __builtin_amdgcn_sched_barrier(0);

#define K3_ITER(KT, S0, S1, A0, A1, D0, D1, BW, BR)  do{                        \
    *(int4v*)(&tl[BW][0][woff]) = S0;  /* tile KT+1 (auto counted-vmcnt wait) */ \
    *(int4v*)(&tl[BW][1][woff]) = S1;                                            \
    {  const int jo3 = ((KT)+3 < 32 ? (KT)+3 : 31)*32;  /* stage tile KT+3 */    \
       S0 = *(const int4v*)(sgp + jo3);                                          \
       S1 = *(const int4v*)(sgp + 1024 + jo3); }                                 \
    bf16x8 af;                                                                   \
    {  float w[8];                                                               \
       _Pragma("unroll")                                                         \
       for (int e = 0; e < 4; ++e){                                              \
         const float u0 = siL + D0[e];                                           \
         w[e]     = A0[e] + fast_exp2(lrelu(u0) - Ci);                           \
         const float u1 = siL + D1[e];                                           \
         w[4 + e] = A1[e] + fast_exp2(lrelu(u1) - Ci);                           \
       }                                                                         \
       const unsigned int p01 = __builtin_amdgcn_perm(__float_as_uint(w[1]), __float_as_uint(w[0]), 0x07060302u); \
       const unsigned int p23 = __builtin_amdgcn_perm(__float_as_uint(w[3]), __float_as_uint(w[2]), 0x07060302u); \
       const unsigned int p45 = __builtin_amdgcn_perm(__float_as_uint(w[5]), __float_as_uint(w[4]), 0x07060302u); \
       const unsigned int p67 = __builtin_amdgcn_perm(__float_as_uint(w[7]), __float_as_uint(w[6]), 0x07060302u); \
       int4v ai = {(int)p01, (int)p23, (int)p45, (int)p67};                      \
       af = *(bf16x8*)&ai;                                                       \
    }                                                                            \
    {  const int jn = ((KT)+2 < 32 ? (KT)+2 : 31)*32;   /* adj/sd for KT+2 */    \
       A0 = *(const f32x4*)(adjrow + jn);                                        \
       A1 = *(const f32x4*)(adjrow + jn + 4);                                    \
       D0 = *(const f32x4*)(sdb + jn);                                           \
       D1 = *(const f32x4*)(sdb + jn + 4); }                                     \
    _Pragma("unroll")                                                            \
    for (int cg = 0; cg < 8; ++cg){                                              \
      const bf16x8 bfv = *(const bf16x8*)(&tl[BR][kh][(cg*16 + lr)*40 + hi*8]);  \
      acc[cg] = __builtin_amdgcn_mfma_f32_16x16x32_bf16(af, bfv, acc[cg], 0, 0, 0); \
    }                                                                            \
    asm volatile("s_waitcnt lgkmcnt(0)" ::: "memory");                           \
    __builtin_amdgcn_s_barrier();                                                \
    __builtin_amdgcn_sched_barrier(0);                                           \
  }while(0)

  for (int kt = 0; kt < 32; kt += 2){
    K3_ITER(kt,     sA0, sA1, aA0, aA1, dA0, dA1, 1, 0);
    K3_ITER(kt + 1, sB0, sB1, aB0, aB1, dB0, dB1, 0, 1);
  }
#undef K3_ITER

  // ---- epilogue: split-K reduce + lrelu + store ----
  if (kh == 1){
#pragma unroll
    for (int cg = 0; cg < 8; ++cg)
#pragma unroll
      for (int q = 0; q < 4; ++q)
        red[(wr*16 + hi*4 + q)*128 + cg*16 + lr] = acc[cg][q];
  }
  __syncthreads();
  if (kh == 0){
#pragma unroll
    for (int cg = 0; cg < 8; ++cg){
#pragma unroll
      for (int q = 0; q < 4; ++q){
        const int rl2 = wr*16 + hi*4 + q;
        const float v = acc[cg][q] + red[rl2*128 + cg*16 + lr];
        out[((long)b*2048 + i0 + rl2)*128 + cg*16 + lr] = lrelu(v);
      }
    }
  }
}

extern "C" void kernel_launch(void* const* d_in, const int* in_sizes, int n_in,
                              void* d_out, int out_size, void* d_ws, size_t ws_size,
                              hipStream_t stream){
  const float* x   = (const float*)d_in[0];
  const float* adj = (const float*)d_in[1];
  const float* W   = (const float*)d_in[2];
  const float* a   = (const float*)d_in[3];
  float* out = (float*)d_out;
  char* ws = (char*)d_ws;

  unsigned short* ht    = (unsigned short*)(ws);              // 4 MB
  float*          ssrcL = (float*)(ws + 4194304);             // 64 KB
  float*          sdstL = (float*)(ws + 4259840);             // 64 KB
  float*          carr  = (float*)(ws + 4325376);             // 64 KB

  k1_fused<<<512,  256, 0, stream>>>(x, W, a, ht, ssrcL, sdstL);
  k2_ml   <<<4096, 256, 0, stream>>>(ssrcL, sdstL, carr);
  k3_main <<<256,  512, 0, stream>>>(adj, ht, ssrcL, sdstL, carr, out);
}